// Round 10
// baseline (730.752 us; speedup 1.0000x reference)
//
#include <hip/hip_runtime.h>
#include <math.h>

#define NNODES 62
#define NDEG 8
#define NGRAPH 800
#define NB 16
#define NT 50
#define NIN 64
#define NCH 128
#define NH 256
#define NCLS 3
#define NTOPK 5
#define EPG (NNODES*NDEG)       // 496 edges per graph
#define E2G (EPG + NNODES)      // 558 incl self loops
#define NTOTAL (NGRAPH*NNODES)  // 49600
#define ETOTAL (NGRAPH*EPG)     // 396800

// ---------------- xr = x@W_r + b_r AND xl = x@W_l + b_l (r7-proven) ----------------
__launch_bounds__(256, 2)
__global__ void k_xrl(const float* __restrict__ x,
                      const float* __restrict__ W_r, const float* __restrict__ b_r,
                      const float* __restrict__ W_l, const float* __restrict__ b_l,
                      float* __restrict__ xr, float* __restrict__ xl) {
    __shared__ __align__(16) float x_s[64 * NIN];      // 16 KB
    __shared__ __align__(16) float wr_s[NIN * NCH];    // 32 KB
    __shared__ __align__(16) float wl_s[NIN * NCH];    // 32 KB
    const int blk = blockIdx.x;                        // 775 blocks
    const int tid = threadIdx.x;
    const int base_v = blk * 64;

    {
        const float4* src = reinterpret_cast<const float4*>(x + (size_t)base_v * NIN);
        float4* dst = reinterpret_cast<float4*>(x_s);
        for (int i = tid; i < 64 * NIN / 4; i += 256) dst[i] = src[i];
        const float4* sr = reinterpret_cast<const float4*>(W_r);
        const float4* sl = reinterpret_cast<const float4*>(W_l);
        float4* dr = reinterpret_cast<float4*>(wr_s);
        float4* dl = reinterpret_cast<float4*>(wl_s);
        for (int i = tid; i < NIN * NCH / 4; i += 256) { dr[i] = sr[i]; dl[i] = sl[i]; }
    }
    __syncthreads();

    const int c4 = (tid & 31) * 4;
    const int ng = tid >> 5;          // 0..7 -> nodes ng*8 .. ng*8+7
    float4 aR[8], aL[8];
    float4 br4 = *reinterpret_cast<const float4*>(b_r + c4);
    float4 bl4 = *reinterpret_cast<const float4*>(b_l + c4);
    #pragma unroll
    for (int j = 0; j < 8; ++j) { aR[j] = br4; aL[j] = bl4; }

    const float* xs = x_s + (ng * 8) * NIN;
    for (int k4 = 0; k4 < NIN; k4 += 4) {
        float4 xv[8];
        #pragma unroll
        for (int j = 0; j < 8; ++j)
            xv[j] = *reinterpret_cast<const float4*>(&xs[j * NIN + k4]);
        #pragma unroll
        for (int kk = 0; kk < 4; ++kk) {
            float4 wr = *reinterpret_cast<const float4*>(&wr_s[(k4 + kk) * NCH + c4]);
            float4 wl = *reinterpret_cast<const float4*>(&wl_s[(k4 + kk) * NCH + c4]);
            #pragma unroll
            for (int j = 0; j < 8; ++j) {
                float xk = (kk == 0) ? xv[j].x : (kk == 1) ? xv[j].y
                         : (kk == 2) ? xv[j].z : xv[j].w;
                aR[j].x += xk * wr.x; aR[j].y += xk * wr.y;
                aR[j].z += xk * wr.z; aR[j].w += xk * wr.w;
                aL[j].x += xk * wl.x; aL[j].y += xk * wl.y;
                aL[j].z += xk * wl.z; aL[j].w += xk * wl.w;
            }
        }
    }
    #pragma unroll
    for (int j = 0; j < 8; ++j) {
        int v = base_v + ng * 8 + j;
        *reinterpret_cast<float4*>(xr + (size_t)v * NCH + c4) = aR[j];
        *reinterpret_cast<float4*>(xl + (size_t)v * NCH + c4) = aL[j];
    }
}

// ---------------- simple transpose ----------------
__global__ void k_transpose(const float* __restrict__ src, float* __restrict__ dst,
                            int rows, int cols) {
    int idx = blockIdx.x * blockDim.x + threadIdx.x;
    if (idx >= rows * cols) return;
    int r = idx / cols;
    int c = idx - r * cols;
    dst[c * rows + r] = src[idx];
}

// ---------------- fused per-graph GATv2 + mean pool: CSR-bucketed (r8-proven) ------------
__launch_bounds__(256, 4)
__global__ void k_gat(const int* __restrict__ ei, const float* __restrict__ eattr,
                      const float* __restrict__ W_e, const float* __restrict__ att,
                      const float* __restrict__ bias_out,
                      const float* __restrict__ xr_all, const float* __restrict__ xl_all,
                      float* __restrict__ g_all) {
    __shared__ __align__(16) float xl_s[NNODES * NCH];  // 31744 B
    __shared__ unsigned short csr_src[E2G];
    __shared__ float csr_attr[E2G];
    __shared__ float csr_e[E2G];
    __shared__ unsigned short off_s[NNODES + 2];
    __shared__ unsigned cur_s[NNODES];
    __shared__ unsigned cnt_s[NNODES];
    __shared__ float asum_s[NNODES];
    __shared__ float la_s[NNODES];
    __shared__ float gacc_s[4 * NCH];

    const int g = blockIdx.x;
    const int tid = threadIdx.x;
    const int base_e = g * EPG;
    const int base_n = g * NNODES;

    for (int v = tid; v < NNODES; v += 256) { asum_s[v] = 0.f; cnt_s[v] = 0u; cur_s[v] = 0u; }
    {
        const float4* src = reinterpret_cast<const float4*>(xl_all + (size_t)base_n * NCH);
        float4* dst = reinterpret_cast<float4*>(xl_s);
        for (int i = tid; i < NNODES * NCH / 4; i += 256) dst[i] = src[i];
    }
    int s0 = -1, d0 = 0, s1 = -1, d1 = 0;
    float a0 = 0.f, a1 = 0.f;
    {
        int j0 = tid * 2, j1 = tid * 2 + 1;
        if (j0 < EPG) { s0 = ei[base_e + j0] - base_n; d0 = ei[ETOTAL + base_e + j0] - base_n; a0 = eattr[base_e + j0]; }
        if (j1 < EPG) { s1 = ei[base_e + j1] - base_n; d1 = ei[ETOTAL + base_e + j1] - base_n; a1 = eattr[base_e + j1]; }
    }
    __syncthreads();

    if (s0 >= 0) { atomicAdd(&cnt_s[d0], 1u); atomicAdd(&asum_s[d0], a0); }
    if (s1 >= 0) { atomicAdd(&cnt_s[d1], 1u); atomicAdd(&asum_s[d1], a1); }
    __syncthreads();

    if (tid < 64) {
        unsigned val = (tid < NNODES) ? (cnt_s[tid] + 1u) : 0u;
        unsigned xsc = val;
        #pragma unroll
        for (int dlt = 1; dlt < 64; dlt <<= 1) {
            unsigned o = __shfl_up(xsc, dlt, 64);
            if (tid >= dlt) xsc += o;
        }
        if (tid < NNODES) {
            off_s[tid] = (unsigned short)(xsc - val);
            la_s[tid] = asum_s[tid] / fmaxf((float)cnt_s[tid], 1.f);
        }
        if (tid == NNODES - 1) off_s[NNODES] = (unsigned short)xsc;
    }
    __syncthreads();

    if (s0 >= 0) { int sl = off_s[d0] + (int)atomicAdd(&cur_s[d0], 1u); csr_src[sl] = (unsigned short)s0; csr_attr[sl] = a0; }
    if (s1 >= 0) { int sl = off_s[d1] + (int)atomicAdd(&cur_s[d1], 1u); csr_src[sl] = (unsigned short)s1; csr_attr[sl] = a1; }
    if (tid < NNODES) { int sl = off_s[tid + 1] - 1; csr_src[sl] = (unsigned short)tid; csr_attr[sl] = la_s[tid]; }
    __syncthreads();

    const int wave = tid >> 6;
    const int lane = tid & 63;
    const int sub = lane & 15;
    const int gslot = wave * 4 + (lane >> 4);   // 0..15
    const int cb = sub * 8;

    float we0[8], at0[8];
    #pragma unroll
    for (int i = 0; i < 8; ++i) { we0[i] = W_e[cb + i]; at0[i] = att[cb + i]; }

    float acc[8];
    #pragma unroll
    for (int i = 0; i < 8; ++i) acc[i] = 0.f;

    for (int v = gslot; v < NNODES; v += 16) {
        const float* xrp = xr_all + (size_t)(base_n + v) * NCH + cb;
        float4 xr0 = *reinterpret_cast<const float4*>(xrp);
        float4 xr1 = *reinterpret_cast<const float4*>(xrp + 4);
        const int lo = off_s[v], hi = off_s[v + 1];
        float m = -INFINITY, ssum = 0.f;
        for (int sl = lo; sl < hi; ++sl) {
            int src = csr_src[sl];
            float a = csr_attr[sl];
            float4 x0 = *reinterpret_cast<const float4*>(&xl_s[src * NCH + cb]);
            float4 x1 = *reinterpret_cast<const float4*>(&xl_s[src * NCH + cb + 4]);
            float mi, t = 0.f;
            mi = x0.x + xr0.x + a * we0[0]; t += (mi >= 0.f ? mi : 0.2f * mi) * at0[0];
            mi = x0.y + xr0.y + a * we0[1]; t += (mi >= 0.f ? mi : 0.2f * mi) * at0[1];
            mi = x0.z + xr0.z + a * we0[2]; t += (mi >= 0.f ? mi : 0.2f * mi) * at0[2];
            mi = x0.w + xr0.w + a * we0[3]; t += (mi >= 0.f ? mi : 0.2f * mi) * at0[3];
            mi = x1.x + xr1.x + a * we0[4]; t += (mi >= 0.f ? mi : 0.2f * mi) * at0[4];
            mi = x1.y + xr1.y + a * we0[5]; t += (mi >= 0.f ? mi : 0.2f * mi) * at0[5];
            mi = x1.z + xr1.z + a * we0[6]; t += (mi >= 0.f ? mi : 0.2f * mi) * at0[6];
            mi = x1.w + xr1.w + a * we0[7]; t += (mi >= 0.f ? mi : 0.2f * mi) * at0[7];
            t += __shfl_xor(t, 1, 64);
            t += __shfl_xor(t, 2, 64);
            t += __shfl_xor(t, 4, 64);
            t += __shfl_xor(t, 8, 64);
            if (sub == 0) csr_e[sl] = t;
            float mn = fmaxf(m, t);
            ssum = ssum * __expf(m - mn) + __expf(t - mn);
            m = mn;
        }
        float inv = 1.f / ssum;
        for (int sl = lo; sl < hi; ++sl) {
            int src = csr_src[sl];
            float al = __expf(csr_e[sl] - m) * inv;
            float4 x0 = *reinterpret_cast<const float4*>(&xl_s[src * NCH + cb]);
            float4 x1 = *reinterpret_cast<const float4*>(&xl_s[src * NCH + cb + 4]);
            acc[0] += al * x0.x; acc[1] += al * x0.y;
            acc[2] += al * x0.z; acc[3] += al * x0.w;
            acc[4] += al * x1.x; acc[5] += al * x1.y;
            acc[6] += al * x1.z; acc[7] += al * x1.w;
        }
    }
    #pragma unroll
    for (int i = 0; i < 8; ++i) {
        acc[i] += __shfl_xor(acc[i], 16, 64);
        acc[i] += __shfl_xor(acc[i], 32, 64);
    }
    if ((lane >> 4) == 0) {
        *reinterpret_cast<float4*>(&gacc_s[wave * NCH + cb]) =
            make_float4(acc[0], acc[1], acc[2], acc[3]);
        *reinterpret_cast<float4*>(&gacc_s[wave * NCH + cb + 4]) =
            make_float4(acc[4], acc[5], acc[6], acc[7]);
    }
    __syncthreads();

    for (int c = tid; c < NCH; c += 256) {
        float v = (gacc_s[c] + gacc_s[NCH + c] + gacc_s[2 * NCH + c] + gacc_s[3 * NCH + c])
                      * (1.f / NNODES) + bias_out[c];
        g_all[(size_t)g * NCH + c] = v;
    }
}

// ---------------- gx_all = g_all @ W_ih^T + b_ih (+ b_hh folded for r,z gates) ----------
__global__ void k_gx(const float* __restrict__ g_all, const float* __restrict__ W_ihT,
                     const float* __restrict__ b_ih, const float* __restrict__ b_hh,
                     float* __restrict__ gx_all) {
    int idx = blockIdx.x * blockDim.x + threadIdx.x;   // over 800*768
    if (idx >= NGRAPH * 3 * NH) return;
    int gi = idx / (3 * NH);
    int o = idx - gi * (3 * NH);
    float acc = b_ih[o] + (o < 2 * NH ? b_hh[o] : 0.f);  // n-gate b_hh stays separate
    const float* grow = g_all + (size_t)gi * NCH;
    for (int c = 0; c < NCH; ++c) acc += grow[c] * W_ihT[c * (3 * NH) + o];
    gx_all[idx] = acc;
}

// ---------------- GRU: one 768-thread block per sequence, W_hh in VGPRs -----------------
// Thread tid owns gh-row tid: 64 float4 of W_hh in registers (256 VGPR; 12 waves/CU at
// 3/SIMD -> 682 VGPR budget). Per step: gx prefetch, 64 broadcast ds_read_b128 of h +
// 256 FMA, two barriers. No inter-block exchange at all.
__launch_bounds__(768, 1)
__global__ void k_gru(const float* __restrict__ gx_all, const float* __restrict__ W_hh,
                      const float* __restrict__ b_hh, float* __restrict__ h_all) {
    __shared__ __align__(16) float h_s[NH];
    __shared__ float gh_s[3 * NH];

    const int b = blockIdx.x;
    const int tid = threadIdx.x;

    float4 Wv[64];
    {
        const float* wr = W_hh + (size_t)tid * NH;
        #pragma unroll
        for (int j = 0; j < 64; ++j)
            Wv[j] = *reinterpret_cast<const float4*>(wr + 4 * j);
    }
    const float bhn = (tid < NH) ? b_hh[2 * NH + tid] : 0.f;

    if (tid < NH) h_s[tid] = 0.f;
    __syncthreads();

    for (int t = 0; t < NT; ++t) {
        // issue gx loads first; the FMA loop below hides their latency
        float gxr = 0.f, gxz = 0.f, gxn = 0.f;
        if (tid < NH) {
            const float* gx = gx_all + (size_t)(b * NT + t) * (3 * NH);
            gxr = gx[tid]; gxz = gx[tid + NH]; gxn = gx[tid + 2 * NH];
        }
        float acc = 0.f;
        #pragma unroll
        for (int j = 0; j < 64; ++j) {
            float4 hv = *reinterpret_cast<const float4*>(&h_s[4 * j]);  // broadcast
            acc += hv.x * Wv[j].x + hv.y * Wv[j].y + hv.z * Wv[j].z + hv.w * Wv[j].w;
        }
        gh_s[tid] = acc;
        __syncthreads();

        if (tid < NH) {
            float r = 1.f / (1.f + expf(-(gxr + gh_s[tid])));
            float z = 1.f / (1.f + expf(-(gxz + gh_s[tid + NH])));
            float n = tanhf(gxn + r * (gh_s[tid + 2 * NH] + bhn));
            float hv = (1.f - z) * n + z * h_s[tid];
            h_s[tid] = hv;
            h_all[(size_t)(b * NT + t) * NH + tid] = hv;
        }
        __syncthreads();
    }
}

// ---------------- classifier: scores[b,t,:] = relu(h @ W1 + b1) @ W2 + b2 ----------------
__launch_bounds__(128)
__global__ void k_cls(const float* __restrict__ h_all,
                      const float* __restrict__ W1, const float* __restrict__ b1,
                      const float* __restrict__ W2, const float* __restrict__ b2,
                      float* __restrict__ sc_all) {
    __shared__ float h_s[NH];
    __shared__ float s1_s[NH / 2];
    const int bt = blockIdx.x;
    const int tid = threadIdx.x;
    h_s[tid] = h_all[(size_t)bt * NH + tid];
    h_s[tid + 128] = h_all[(size_t)bt * NH + tid + 128];
    __syncthreads();
    float acc = b1[tid];
    #pragma unroll 8
    for (int k = 0; k < NH; ++k) acc += h_s[k] * W1[k * (NH / 2) + tid];
    s1_s[tid] = fmaxf(acc, 0.f);
    __syncthreads();
    if (tid < NCLS) {
        float a = b2[tid];
        for (int k = 0; k < NH / 2; ++k) a += s1_s[k] * W2[k * NCLS + tid];
        sc_all[bt * NCLS + tid] = a;
    }
}

// ---------------- top-k over time per (b, class) ----------------
__global__ void k_topk(const float* __restrict__ sc_all, float* __restrict__ out) {
    int tid = threadIdx.x;
    if (tid >= NB * NCLS) return;
    int b = tid / NCLS;
    int c = tid - b * NCLS;
    float vals[NT];
    for (int t = 0; t < NT; ++t) vals[t] = sc_all[(b * NT + t) * NCLS + c];
    float sum = 0.f;
    for (int k = 0; k < NTOPK; ++k) {
        float best = -INFINITY; int bi = 0;
        for (int t = 0; t < NT; ++t) {
            if (vals[t] > best) { best = vals[t]; bi = t; }
        }
        vals[bi] = -INFINITY;
        sum += best;
        out[NB * NCLS + b * (NTOPK * NCLS) + k * NCLS + c] = (float)bi;
    }
    out[b * NCLS + c] = sum * (1.f / NTOPK);
}

extern "C" void kernel_launch(void* const* d_in, const int* in_sizes, int n_in,
                              void* d_out, int out_size, void* d_ws, size_t ws_size,
                              hipStream_t stream) {
    const float* x        = (const float*)d_in[0];
    const int*   ei       = (const int*)  d_in[1];
    const float* eattr    = (const float*)d_in[2];
    const float* W_l      = (const float*)d_in[3];
    const float* b_l      = (const float*)d_in[4];
    const float* W_r      = (const float*)d_in[5];
    const float* b_r      = (const float*)d_in[6];
    const float* W_e      = (const float*)d_in[7];
    const float* att      = (const float*)d_in[8];
    const float* bias_out = (const float*)d_in[9];
    const float* W_ih     = (const float*)d_in[10];
    const float* W_hh     = (const float*)d_in[11];
    const float* b_ih     = (const float*)d_in[12];
    const float* b_hh     = (const float*)d_in[13];
    const float* W1       = (const float*)d_in[14];
    const float* b1       = (const float*)d_in[15];
    const float* W2       = (const float*)d_in[16];
    const float* b2       = (const float*)d_in[17];
    float* out = (float*)d_out;

    float* ws = (float*)d_ws;
    float* xr_all = ws;                                   // 49600*128
    float* xl_all = xr_all + (size_t)NTOTAL * NCH;        // 49600*128
    float* g_all  = xl_all + (size_t)NTOTAL * NCH;        // 800*128
    float* gx_all = g_all + NGRAPH * NCH;                 // 800*768
    float* W_ihT  = gx_all + NGRAPH * 3 * NH;             // 128*768
    float* h_all  = W_ihT + NCH * 3 * NH;                 // 800*256
    float* sc_all = h_all + (size_t)NGRAPH * NH;          // 800*3

    k_xrl<<<NTOTAL / 64, 256, 0, stream>>>(x, W_r, b_r, W_l, b_l, xr_all, xl_all);
    k_transpose<<<(3 * NH * NCH + 255) / 256, 256, 0, stream>>>(W_ih, W_ihT, 3 * NH, NCH);
    k_gat<<<NGRAPH, 256, 0, stream>>>(ei, eattr, W_e, att, bias_out, xr_all, xl_all, g_all);
    k_gx<<<(NGRAPH * 3 * NH + 255) / 256, 256, 0, stream>>>(g_all, W_ihT, b_ih, b_hh, gx_all);
    k_gru<<<NB, 768, 0, stream>>>(gx_all, W_hh, b_hh, h_all);
    k_cls<<<NB * NT, 128, 0, stream>>>(h_all, W1, b1, W2, b2, sc_all);
    k_topk<<<1, 64, 0, stream>>>(sc_all, out);
}

// Round 11
// 212.902 us; speedup vs baseline: 3.4323x; 3.4323x over previous
//
#include <hip/hip_runtime.h>
#include <math.h>

#define NNODES 62
#define NDEG 8
#define NGRAPH 800
#define NB 16
#define NT 50
#define NIN 64
#define NCH 128
#define NH 256
#define NCLS 3
#define NTOPK 5
#define NSL 16                  // h-slices per batch (blocks per sequence)
#define EPG (NNODES*NDEG)       // 496 edges per graph
#define E2G (EPG + NNODES)      // 558 incl self loops
#define NTOTAL (NGRAPH*NNODES)  // 49600
#define ETOTAL (NGRAPH*EPG)     // 396800
#define NXB (NTOTAL/64)         // 775 main xrl blocks
#define TTB 128                 // transpose tail blocks appended to k_xrl grid

// ---------------- xr = x@W_r + b_r AND xl = x@W_l + b_l (r7-proven) ----------------
// Tail blocks (>=NXB) transpose W_ih for k_gx instead (folds the old k_transpose launch).
__launch_bounds__(256, 2)
__global__ void k_xrl(const float* __restrict__ x,
                      const float* __restrict__ W_r, const float* __restrict__ b_r,
                      const float* __restrict__ W_l, const float* __restrict__ b_l,
                      const float* __restrict__ W_ih, float* __restrict__ W_ihT,
                      float* __restrict__ xr, float* __restrict__ xl) {
    __shared__ __align__(16) float x_s[64 * NIN];      // 16 KB
    __shared__ __align__(16) float wr_s[NIN * NCH];    // 32 KB
    __shared__ __align__(16) float wl_s[NIN * NCH];    // 32 KB
    const int blk = blockIdx.x;
    const int tid = threadIdx.x;
    if (blk >= NXB) {
        for (int idx = (blk - NXB) * 256 + tid; idx < 3 * NH * NCH; idx += TTB * 256) {
            int r = idx / NCH, c = idx - r * NCH;
            W_ihT[c * (3 * NH) + r] = W_ih[idx];
        }
        return;
    }
    const int base_v = blk * 64;

    {
        const float4* src = reinterpret_cast<const float4*>(x + (size_t)base_v * NIN);
        float4* dst = reinterpret_cast<float4*>(x_s);
        for (int i = tid; i < 64 * NIN / 4; i += 256) dst[i] = src[i];
        const float4* sr = reinterpret_cast<const float4*>(W_r);
        const float4* sl = reinterpret_cast<const float4*>(W_l);
        float4* dr = reinterpret_cast<float4*>(wr_s);
        float4* dl = reinterpret_cast<float4*>(wl_s);
        for (int i = tid; i < NIN * NCH / 4; i += 256) { dr[i] = sr[i]; dl[i] = sl[i]; }
    }
    __syncthreads();

    const int c4 = (tid & 31) * 4;
    const int ng = tid >> 5;          // 0..7 -> nodes ng*8 .. ng*8+7
    float4 aR[8], aL[8];
    float4 br4 = *reinterpret_cast<const float4*>(b_r + c4);
    float4 bl4 = *reinterpret_cast<const float4*>(b_l + c4);
    #pragma unroll
    for (int j = 0; j < 8; ++j) { aR[j] = br4; aL[j] = bl4; }

    const float* xs = x_s + (ng * 8) * NIN;
    for (int k4 = 0; k4 < NIN; k4 += 4) {
        float4 xv[8];
        #pragma unroll
        for (int j = 0; j < 8; ++j)
            xv[j] = *reinterpret_cast<const float4*>(&xs[j * NIN + k4]);
        #pragma unroll
        for (int kk = 0; kk < 4; ++kk) {
            float4 wr = *reinterpret_cast<const float4*>(&wr_s[(k4 + kk) * NCH + c4]);
            float4 wl = *reinterpret_cast<const float4*>(&wl_s[(k4 + kk) * NCH + c4]);
            #pragma unroll
            for (int j = 0; j < 8; ++j) {
                float xk = (kk == 0) ? xv[j].x : (kk == 1) ? xv[j].y
                         : (kk == 2) ? xv[j].z : xv[j].w;
                aR[j].x += xk * wr.x; aR[j].y += xk * wr.y;
                aR[j].z += xk * wr.z; aR[j].w += xk * wr.w;
                aL[j].x += xk * wl.x; aL[j].y += xk * wl.y;
                aL[j].z += xk * wl.z; aL[j].w += xk * wl.w;
            }
        }
    }
    #pragma unroll
    for (int j = 0; j < 8; ++j) {
        int v = base_v + ng * 8 + j;
        *reinterpret_cast<float4*>(xr + (size_t)v * NCH + c4) = aR[j];
        *reinterpret_cast<float4*>(xl + (size_t)v * NCH + c4) = aL[j];
    }
}

// ---------------- fused per-graph GATv2 + mean pool: CSR-bucketed (r8-proven) ------------
__launch_bounds__(256, 4)
__global__ void k_gat(const int* __restrict__ ei, const float* __restrict__ eattr,
                      const float* __restrict__ W_e, const float* __restrict__ att,
                      const float* __restrict__ bias_out,
                      const float* __restrict__ xr_all, const float* __restrict__ xl_all,
                      float* __restrict__ g_all) {
    __shared__ __align__(16) float xl_s[NNODES * NCH];  // 31744 B
    __shared__ unsigned short csr_src[E2G];
    __shared__ float csr_attr[E2G];
    __shared__ float csr_e[E2G];
    __shared__ unsigned short off_s[NNODES + 2];
    __shared__ unsigned cur_s[NNODES];
    __shared__ unsigned cnt_s[NNODES];
    __shared__ float asum_s[NNODES];
    __shared__ float la_s[NNODES];
    __shared__ float gacc_s[4 * NCH];

    const int g = blockIdx.x;
    const int tid = threadIdx.x;
    const int base_e = g * EPG;
    const int base_n = g * NNODES;

    for (int v = tid; v < NNODES; v += 256) { asum_s[v] = 0.f; cnt_s[v] = 0u; cur_s[v] = 0u; }
    {
        const float4* src = reinterpret_cast<const float4*>(xl_all + (size_t)base_n * NCH);
        float4* dst = reinterpret_cast<float4*>(xl_s);
        for (int i = tid; i < NNODES * NCH / 4; i += 256) dst[i] = src[i];
    }
    int s0 = -1, d0 = 0, s1 = -1, d1 = 0;
    float a0 = 0.f, a1 = 0.f;
    {
        int j0 = tid * 2, j1 = tid * 2 + 1;
        if (j0 < EPG) { s0 = ei[base_e + j0] - base_n; d0 = ei[ETOTAL + base_e + j0] - base_n; a0 = eattr[base_e + j0]; }
        if (j1 < EPG) { s1 = ei[base_e + j1] - base_n; d1 = ei[ETOTAL + base_e + j1] - base_n; a1 = eattr[base_e + j1]; }
    }
    __syncthreads();

    if (s0 >= 0) { atomicAdd(&cnt_s[d0], 1u); atomicAdd(&asum_s[d0], a0); }
    if (s1 >= 0) { atomicAdd(&cnt_s[d1], 1u); atomicAdd(&asum_s[d1], a1); }
    __syncthreads();

    if (tid < 64) {
        unsigned val = (tid < NNODES) ? (cnt_s[tid] + 1u) : 0u;
        unsigned xsc = val;
        #pragma unroll
        for (int dlt = 1; dlt < 64; dlt <<= 1) {
            unsigned o = __shfl_up(xsc, dlt, 64);
            if (tid >= dlt) xsc += o;
        }
        if (tid < NNODES) {
            off_s[tid] = (unsigned short)(xsc - val);
            la_s[tid] = asum_s[tid] / fmaxf((float)cnt_s[tid], 1.f);
        }
        if (tid == NNODES - 1) off_s[NNODES] = (unsigned short)xsc;
    }
    __syncthreads();

    if (s0 >= 0) { int sl = off_s[d0] + (int)atomicAdd(&cur_s[d0], 1u); csr_src[sl] = (unsigned short)s0; csr_attr[sl] = a0; }
    if (s1 >= 0) { int sl = off_s[d1] + (int)atomicAdd(&cur_s[d1], 1u); csr_src[sl] = (unsigned short)s1; csr_attr[sl] = a1; }
    if (tid < NNODES) { int sl = off_s[tid + 1] - 1; csr_src[sl] = (unsigned short)tid; csr_attr[sl] = la_s[tid]; }
    __syncthreads();

    const int wave = tid >> 6;
    const int lane = tid & 63;
    const int sub = lane & 15;
    const int gslot = wave * 4 + (lane >> 4);   // 0..15
    const int cb = sub * 8;

    float we0[8], at0[8];
    #pragma unroll
    for (int i = 0; i < 8; ++i) { we0[i] = W_e[cb + i]; at0[i] = att[cb + i]; }

    float acc[8];
    #pragma unroll
    for (int i = 0; i < 8; ++i) acc[i] = 0.f;

    for (int v = gslot; v < NNODES; v += 16) {
        const float* xrp = xr_all + (size_t)(base_n + v) * NCH + cb;
        float4 xr0 = *reinterpret_cast<const float4*>(xrp);
        float4 xr1 = *reinterpret_cast<const float4*>(xrp + 4);
        const int lo = off_s[v], hi = off_s[v + 1];
        float m = -INFINITY, ssum = 0.f;
        for (int sl = lo; sl < hi; ++sl) {
            int src = csr_src[sl];
            float a = csr_attr[sl];
            float4 x0 = *reinterpret_cast<const float4*>(&xl_s[src * NCH + cb]);
            float4 x1 = *reinterpret_cast<const float4*>(&xl_s[src * NCH + cb + 4]);
            float mi, t = 0.f;
            mi = x0.x + xr0.x + a * we0[0]; t += (mi >= 0.f ? mi : 0.2f * mi) * at0[0];
            mi = x0.y + xr0.y + a * we0[1]; t += (mi >= 0.f ? mi : 0.2f * mi) * at0[1];
            mi = x0.z + xr0.z + a * we0[2]; t += (mi >= 0.f ? mi : 0.2f * mi) * at0[2];
            mi = x0.w + xr0.w + a * we0[3]; t += (mi >= 0.f ? mi : 0.2f * mi) * at0[3];
            mi = x1.x + xr1.x + a * we0[4]; t += (mi >= 0.f ? mi : 0.2f * mi) * at0[4];
            mi = x1.y + xr1.y + a * we0[5]; t += (mi >= 0.f ? mi : 0.2f * mi) * at0[5];
            mi = x1.z + xr1.z + a * we0[6]; t += (mi >= 0.f ? mi : 0.2f * mi) * at0[6];
            mi = x1.w + xr1.w + a * we0[7]; t += (mi >= 0.f ? mi : 0.2f * mi) * at0[7];
            t += __shfl_xor(t, 1, 64);
            t += __shfl_xor(t, 2, 64);
            t += __shfl_xor(t, 4, 64);
            t += __shfl_xor(t, 8, 64);
            if (sub == 0) csr_e[sl] = t;
            float mn = fmaxf(m, t);
            ssum = ssum * __expf(m - mn) + __expf(t - mn);
            m = mn;
        }
        float inv = 1.f / ssum;
        for (int sl = lo; sl < hi; ++sl) {
            int src = csr_src[sl];
            float al = __expf(csr_e[sl] - m) * inv;
            float4 x0 = *reinterpret_cast<const float4*>(&xl_s[src * NCH + cb]);
            float4 x1 = *reinterpret_cast<const float4*>(&xl_s[src * NCH + cb + 4]);
            acc[0] += al * x0.x; acc[1] += al * x0.y;
            acc[2] += al * x0.z; acc[3] += al * x0.w;
            acc[4] += al * x1.x; acc[5] += al * x1.y;
            acc[6] += al * x1.z; acc[7] += al * x1.w;
        }
    }
    #pragma unroll
    for (int i = 0; i < 8; ++i) {
        acc[i] += __shfl_xor(acc[i], 16, 64);
        acc[i] += __shfl_xor(acc[i], 32, 64);
    }
    if ((lane >> 4) == 0) {
        *reinterpret_cast<float4*>(&gacc_s[wave * NCH + cb]) =
            make_float4(acc[0], acc[1], acc[2], acc[3]);
        *reinterpret_cast<float4*>(&gacc_s[wave * NCH + cb + 4]) =
            make_float4(acc[4], acc[5], acc[6], acc[7]);
    }
    __syncthreads();

    for (int c = tid; c < NCH; c += 256) {
        float v = (gacc_s[c] + gacc_s[NCH + c] + gacc_s[2 * NCH + c] + gacc_s[3 * NCH + c])
                      * (1.f / NNODES) + bias_out[c];
        g_all[(size_t)g * NCH + c] = v;
    }
}

// ---------------- gx_all = g_all @ W_ih^T + biases; also zeroes h_pub (replay-safe) ------
__global__ void k_gx(const float* __restrict__ g_all, const float* __restrict__ W_ihT,
                     const float* __restrict__ b_ih, const float* __restrict__ b_hh,
                     float* __restrict__ gx_all, unsigned long long* __restrict__ h_pub) {
    if (blockIdx.x < 32)
        h_pub[(size_t)blockIdx.x * 256 + threadIdx.x] = 0ull;   // 8192 u64 total
    int idx = blockIdx.x * blockDim.x + threadIdx.x;   // over 800*768
    if (idx >= NGRAPH * 3 * NH) return;
    int gi = idx / (3 * NH);
    int o = idx - gi * (3 * NH);
    float acc = b_ih[o] + (o < 2 * NH ? b_hh[o] : 0.f);  // n-gate b_hh stays separate
    const float* grow = g_all + (size_t)gi * NCH;
    for (int c = 0; c < NCH; ++c) acc += grow[c] * W_ihT[c * (3 * NH) + o];
    gx_all[idx] = acc;
}

// ---------------- GRU: 256 blocks (16 batch x 16 slice), W_hh register-resident -----------
// r7-proven protocol. ONLY change: __launch_bounds__(256, 1) -> 512-VGPR budget so the
// Wv[16] tile (64 VGPRs) actually stays register-resident (r7 showed VGPR_Count=56 ->
// compiler was rematerializing W from cache every step under the default occupancy target).
__launch_bounds__(256, 1)
__global__ void k_gru(const float* __restrict__ gx_all, const float* __restrict__ W_hh,
                      const float* __restrict__ b_hh, float* __restrict__ h_all,
                      unsigned long long* __restrict__ h_pub) {
    __shared__ __align__(16) float h_s[NH];
    __shared__ float gh_s[48];
    __shared__ float gx_s[2][48];

    const int bid = blockIdx.x;
    const int b = bid >> 4;
    const int s = bid & 15;
    const int tid = threadIdx.x;
    const int wv = tid >> 6;
    const int g = tid >> 2;          // row 0..47 (tid<192)
    const int l = tid & 3;           // k-quarter within row

    float4 Wv[16];
    if (tid < 192) {
        int row = (g < 16) ? (NSL * s + g)
                : (g < 32) ? (NH + NSL * s + (g - 16))
                           : (2 * NH + NSL * s + (g - 32));
        const float* wr = W_hh + (size_t)row * NH + 64 * l;
        #pragma unroll
        for (int j = 0; j < 16; ++j) {
            int jeff = (j + 2 * l) & 15;           // bank-stagger (conflict-free h reads)
            Wv[j] = *reinterpret_cast<const float4*>(wr + 4 * jeff);
        }
    }
    const float bhn = (tid < NSL) ? b_hh[2 * NH + NSL * s + tid] : 0.f;
    const int own_lo = NSL * s, own_hi = NSL * s + NSL;

    for (int i = tid; i < NH; i += 256) h_s[i] = 0.f;
    if (wv == 3) {
        int i = tid - 192;
        if (i < 48) {
            int o = (i < 16) ? (NSL * s + i) : (i < 32) ? (NH + NSL * s + i - 16)
                                                        : (2 * NH + NSL * s + i - 32);
            gx_s[0][i] = gx_all[(size_t)(b * NT + 0) * (3 * NH) + o];
        }
    }
    __syncthreads();

    for (int t = 0; t < NT; ++t) {
        if (wv == 3) {
            int i = tid - 192;
            if (i < 48 && t + 1 < NT) {
                int o = (i < 16) ? (NSL * s + i) : (i < 32) ? (NH + NSL * s + i - 16)
                                                            : (2 * NH + NSL * s + i - 32);
                gx_s[(t + 1) & 1][i] = gx_all[(size_t)(b * NT + t + 1) * (3 * NH) + o];
            }
        } else {
            float a0 = 0.f, a1 = 0.f, a2 = 0.f, a3 = 0.f;
            #pragma unroll
            for (int j = 0; j < 16; ++j) {
                int jeff = (j + 2 * l) & 15;
                float4 hv = *reinterpret_cast<const float4*>(&h_s[64 * l + 4 * jeff]);
                float4 w = Wv[j];
                a0 += w.x * hv.x; a1 += w.y * hv.y; a2 += w.z * hv.z; a3 += w.w * hv.w;
            }
            float acc = (a0 + a1) + (a2 + a3);
            acc += __shfl_xor(acc, 1, 64);
            acc += __shfl_xor(acc, 2, 64);
            if (l == 0) gh_s[g] = acc;
        }
        __syncthreads();

        const int par = (t + 1) & 1;
        if (tid < NSL) {
            const float* gx = gx_s[t & 1];
            float r = 1.f / (1.f + expf(-(gx[tid] + gh_s[tid])));
            float z = 1.f / (1.f + expf(-(gx[16 + tid] + gh_s[16 + tid])));
            float n = tanhf(gx[32 + tid] + r * (gh_s[32 + tid] + bhn));
            int o = own_lo + tid;
            float hv = (1.f - z) * n + z * h_s[o];
            h_all[(size_t)(b * NT + t) * NH + o] = hv;
            unsigned long long w = ((unsigned long long)(unsigned)(t + 1) << 32)
                                 | (unsigned long long)__float_as_uint(hv);
            __hip_atomic_store(&h_pub[((size_t)b * 2 + par) * NH + o], w,
                               __ATOMIC_RELAXED, __HIP_MEMORY_SCOPE_AGENT);
            h_s[o] = hv;
        }
        if (tid < own_lo || tid >= own_hi) {
            const unsigned long long* p = &h_pub[((size_t)b * 2 + par) * NH + tid];
            unsigned long long w;
            const unsigned target = (unsigned)(t + 1);
            while ((unsigned)((w = __hip_atomic_load(p, __ATOMIC_RELAXED,
                                                     __HIP_MEMORY_SCOPE_AGENT)) >> 32) != target)
                __builtin_amdgcn_s_sleep(1);
            h_s[tid] = __uint_as_float((unsigned)w);
        }
        __syncthreads();
    }
}

// ---------------- classifier: scores[b,t,:] = relu(h @ W1 + b1) @ W2 + b2 ----------------
__launch_bounds__(128)
__global__ void k_cls(const float* __restrict__ h_all,
                      const float* __restrict__ W1, const float* __restrict__ b1,
                      const float* __restrict__ W2, const float* __restrict__ b2,
                      float* __restrict__ sc_all) {
    __shared__ float h_s[NH];
    __shared__ float s1_s[NH / 2];
    const int bt = blockIdx.x;
    const int tid = threadIdx.x;
    h_s[tid] = h_all[(size_t)bt * NH + tid];
    h_s[tid + 128] = h_all[(size_t)bt * NH + tid + 128];
    __syncthreads();
    float acc = b1[tid];
    #pragma unroll 8
    for (int k = 0; k < NH; ++k) acc += h_s[k] * W1[k * (NH / 2) + tid];
    s1_s[tid] = fmaxf(acc, 0.f);
    __syncthreads();
    if (tid < NCLS) {
        float a = b2[tid];
        for (int k = 0; k < NH / 2; ++k) a += s1_s[k] * W2[k * NCLS + tid];
        sc_all[bt * NCLS + tid] = a;
    }
}

// ---------------- top-k over time per (b, class) ----------------
__global__ void k_topk(const float* __restrict__ sc_all, float* __restrict__ out) {
    int tid = threadIdx.x;
    if (tid >= NB * NCLS) return;
    int b = tid / NCLS;
    int c = tid - b * NCLS;
    float vals[NT];
    for (int t = 0; t < NT; ++t) vals[t] = sc_all[(b * NT + t) * NCLS + c];
    float sum = 0.f;
    for (int k = 0; k < NTOPK; ++k) {
        float best = -INFINITY; int bi = 0;
        for (int t = 0; t < NT; ++t) {
            if (vals[t] > best) { best = vals[t]; bi = t; }
        }
        vals[bi] = -INFINITY;
        sum += best;
        out[NB * NCLS + b * (NTOPK * NCLS) + k * NCLS + c] = (float)bi;
    }
    out[b * NCLS + c] = sum * (1.f / NTOPK);
}

extern "C" void kernel_launch(void* const* d_in, const int* in_sizes, int n_in,
                              void* d_out, int out_size, void* d_ws, size_t ws_size,
                              hipStream_t stream) {
    const float* x        = (const float*)d_in[0];
    const int*   ei       = (const int*)  d_in[1];
    const float* eattr    = (const float*)d_in[2];
    const float* W_l      = (const float*)d_in[3];
    const float* b_l      = (const float*)d_in[4];
    const float* W_r      = (const float*)d_in[5];
    const float* b_r      = (const float*)d_in[6];
    const float* W_e      = (const float*)d_in[7];
    const float* att      = (const float*)d_in[8];
    const float* bias_out = (const float*)d_in[9];
    const float* W_ih     = (const float*)d_in[10];
    const float* W_hh     = (const float*)d_in[11];
    const float* b_ih     = (const float*)d_in[12];
    const float* b_hh     = (const float*)d_in[13];
    const float* W1       = (const float*)d_in[14];
    const float* b1       = (const float*)d_in[15];
    const float* W2       = (const float*)d_in[16];
    const float* b2       = (const float*)d_in[17];
    float* out = (float*)d_out;

    float* ws = (float*)d_ws;
    float* xr_all = ws;                                   // 49600*128 (dead after k_gat)
    float* xl_all = xr_all + (size_t)NTOTAL * NCH;        // 49600*128 (dead after k_gat)
    float* g_all  = xl_all + (size_t)NTOTAL * NCH;        // 800*128
    float* gx_all = g_all + NGRAPH * NCH;                 // 800*768
    float* W_ihT  = gx_all + NGRAPH * 3 * NH;             // 128*768
    float* h_all  = W_ihT + NCH * 3 * NH;                 // 800*256
    float* sc_all = h_all + (size_t)NGRAPH * NH;          // 800*3
    // packed h-exchange buffer aliases the (dead-after-gat) xr_all region
    unsigned long long* h_pub = (unsigned long long*)xr_all;   // 16*2*256 u64 = 64 KB

    k_xrl<<<NXB + TTB, 256, 0, stream>>>(x, W_r, b_r, W_l, b_l, W_ih, W_ihT, xr_all, xl_all);
    k_gat<<<NGRAPH, 256, 0, stream>>>(ei, eattr, W_e, att, bias_out, xr_all, xl_all, g_all);
    k_gx<<<(NGRAPH * 3 * NH + 255) / 256, 256, 0, stream>>>(g_all, W_ihT, b_ih, b_hh,
                                                            gx_all, h_pub);
    k_gru<<<NB * NSL, 256, 0, stream>>>(gx_all, W_hh, b_hh, h_all, h_pub);
    k_cls<<<NB * NT, 128, 0, stream>>>(h_all, W1, b1, W2, b2, sc_all);
    k_topk<<<1, 64, 0, stream>>>(sc_all, out);
}

// Round 12
// 212.084 us; speedup vs baseline: 3.4456x; 1.0039x over previous
//
#include <hip/hip_runtime.h>
#include <math.h>

#define NNODES 62
#define NDEG 8
#define NGRAPH 800
#define NB 16
#define NT 50
#define NIN 64
#define NCH 128
#define NH 256
#define NCLS 3
#define NTOPK 5
#define NSL 16                  // h-slices per batch (blocks per sequence)
#define EPG (NNODES*NDEG)       // 496 edges per graph
#define E2G (EPG + NNODES)      // 558 incl self loops
#define NTOTAL (NGRAPH*NNODES)  // 49600
#define ETOTAL (NGRAPH*EPG)     // 396800
#define NXB (NTOTAL/64)         // 775 main xrl blocks
#define TTB 96                  // transpose tail blocks appended to k_xrl grid

// ---------------- xr = x@W_r + b_r AND xl = x@W_l + b_l ----------------
// 512 threads/block, 2 blocks/CU -> 4 waves/SIMD (TLP hides LDS latency; r7's 256-thread
// version ran 2 waves/SIMD and stalled on ds_read->FMA chains). Per thread: 4 nodes x
// 4 ch x {r,l} = 32 accumulators. Tail blocks transpose W_ih for k_gx.
__launch_bounds__(512, 4)
__global__ void k_xrl(const float* __restrict__ x,
                      const float* __restrict__ W_r, const float* __restrict__ b_r,
                      const float* __restrict__ W_l, const float* __restrict__ b_l,
                      const float* __restrict__ W_ih, float* __restrict__ W_ihT,
                      float* __restrict__ xr, float* __restrict__ xl) {
    __shared__ __align__(16) float x_s[64 * NIN];      // 16 KB
    __shared__ __align__(16) float wr_s[NIN * NCH];    // 32 KB
    __shared__ __align__(16) float wl_s[NIN * NCH];    // 32 KB
    const int blk = blockIdx.x;
    const int tid = threadIdx.x;
    if (blk >= NXB) {
        for (int idx = (blk - NXB) * 512 + tid; idx < 3 * NH * NCH; idx += TTB * 512) {
            int r = idx / NCH, c = idx - r * NCH;
            W_ihT[c * (3 * NH) + r] = W_ih[idx];
        }
        return;
    }
    const int base_v = blk * 64;

    {
        const float4* src = reinterpret_cast<const float4*>(x + (size_t)base_v * NIN);
        float4* dst = reinterpret_cast<float4*>(x_s);
        for (int i = tid; i < 64 * NIN / 4; i += 512) dst[i] = src[i];
        const float4* sr = reinterpret_cast<const float4*>(W_r);
        const float4* sl = reinterpret_cast<const float4*>(W_l);
        float4* dr = reinterpret_cast<float4*>(wr_s);
        float4* dl = reinterpret_cast<float4*>(wl_s);
        for (int i = tid; i < NIN * NCH / 4; i += 512) { dr[i] = sr[i]; dl[i] = sl[i]; }
    }
    __syncthreads();

    const int c4 = (tid & 31) * 4;
    const int ng = tid >> 5;          // 0..15 -> nodes ng*4 .. ng*4+3
    float4 aR[4], aL[4];
    float4 br4 = *reinterpret_cast<const float4*>(b_r + c4);
    float4 bl4 = *reinterpret_cast<const float4*>(b_l + c4);
    #pragma unroll
    for (int j = 0; j < 4; ++j) { aR[j] = br4; aL[j] = bl4; }

    const float* xs = x_s + (ng * 4) * NIN;
    for (int k4 = 0; k4 < NIN; k4 += 4) {
        float4 xv[4];
        #pragma unroll
        for (int j = 0; j < 4; ++j)
            xv[j] = *reinterpret_cast<const float4*>(&xs[j * NIN + k4]);   // broadcast b128
        #pragma unroll
        for (int kk = 0; kk < 4; ++kk) {
            float4 wr = *reinterpret_cast<const float4*>(&wr_s[(k4 + kk) * NCH + c4]);
            float4 wl = *reinterpret_cast<const float4*>(&wl_s[(k4 + kk) * NCH + c4]);
            #pragma unroll
            for (int j = 0; j < 4; ++j) {
                float xk = (kk == 0) ? xv[j].x : (kk == 1) ? xv[j].y
                         : (kk == 2) ? xv[j].z : xv[j].w;
                aR[j].x += xk * wr.x; aR[j].y += xk * wr.y;
                aR[j].z += xk * wr.z; aR[j].w += xk * wr.w;
                aL[j].x += xk * wl.x; aL[j].y += xk * wl.y;
                aL[j].z += xk * wl.z; aL[j].w += xk * wl.w;
            }
        }
    }
    #pragma unroll
    for (int j = 0; j < 4; ++j) {
        int v = base_v + ng * 4 + j;
        *reinterpret_cast<float4*>(xr + (size_t)v * NCH + c4) = aR[j];
        *reinterpret_cast<float4*>(xl + (size_t)v * NCH + c4) = aL[j];
    }
}

// ---------------- fused per-graph GATv2 + mean pool: CSR-bucketed (r8-proven) ------------
__launch_bounds__(256, 4)
__global__ void k_gat(const int* __restrict__ ei, const float* __restrict__ eattr,
                      const float* __restrict__ W_e, const float* __restrict__ att,
                      const float* __restrict__ bias_out,
                      const float* __restrict__ xr_all, const float* __restrict__ xl_all,
                      float* __restrict__ g_all) {
    __shared__ __align__(16) float xl_s[NNODES * NCH];  // 31744 B
    __shared__ unsigned short csr_src[E2G];
    __shared__ float csr_attr[E2G];
    __shared__ float csr_e[E2G];
    __shared__ unsigned short off_s[NNODES + 2];
    __shared__ unsigned cur_s[NNODES];
    __shared__ unsigned cnt_s[NNODES];
    __shared__ float asum_s[NNODES];
    __shared__ float la_s[NNODES];
    __shared__ float gacc_s[4 * NCH];

    const int g = blockIdx.x;
    const int tid = threadIdx.x;
    const int base_e = g * EPG;
    const int base_n = g * NNODES;

    for (int v = tid; v < NNODES; v += 256) { asum_s[v] = 0.f; cnt_s[v] = 0u; cur_s[v] = 0u; }
    {
        const float4* src = reinterpret_cast<const float4*>(xl_all + (size_t)base_n * NCH);
        float4* dst = reinterpret_cast<float4*>(xl_s);
        for (int i = tid; i < NNODES * NCH / 4; i += 256) dst[i] = src[i];
    }
    int s0 = -1, d0 = 0, s1 = -1, d1 = 0;
    float a0 = 0.f, a1 = 0.f;
    {
        int j0 = tid * 2, j1 = tid * 2 + 1;
        if (j0 < EPG) { s0 = ei[base_e + j0] - base_n; d0 = ei[ETOTAL + base_e + j0] - base_n; a0 = eattr[base_e + j0]; }
        if (j1 < EPG) { s1 = ei[base_e + j1] - base_n; d1 = ei[ETOTAL + base_e + j1] - base_n; a1 = eattr[base_e + j1]; }
    }
    __syncthreads();

    if (s0 >= 0) { atomicAdd(&cnt_s[d0], 1u); atomicAdd(&asum_s[d0], a0); }
    if (s1 >= 0) { atomicAdd(&cnt_s[d1], 1u); atomicAdd(&asum_s[d1], a1); }
    __syncthreads();

    if (tid < 64) {
        unsigned val = (tid < NNODES) ? (cnt_s[tid] + 1u) : 0u;
        unsigned xsc = val;
        #pragma unroll
        for (int dlt = 1; dlt < 64; dlt <<= 1) {
            unsigned o = __shfl_up(xsc, dlt, 64);
            if (tid >= dlt) xsc += o;
        }
        if (tid < NNODES) {
            off_s[tid] = (unsigned short)(xsc - val);
            la_s[tid] = asum_s[tid] / fmaxf((float)cnt_s[tid], 1.f);
        }
        if (tid == NNODES - 1) off_s[NNODES] = (unsigned short)xsc;
    }
    __syncthreads();

    if (s0 >= 0) { int sl = off_s[d0] + (int)atomicAdd(&cur_s[d0], 1u); csr_src[sl] = (unsigned short)s0; csr_attr[sl] = a0; }
    if (s1 >= 0) { int sl = off_s[d1] + (int)atomicAdd(&cur_s[d1], 1u); csr_src[sl] = (unsigned short)s1; csr_attr[sl] = a1; }
    if (tid < NNODES) { int sl = off_s[tid + 1] - 1; csr_src[sl] = (unsigned short)tid; csr_attr[sl] = la_s[tid]; }
    __syncthreads();

    const int wave = tid >> 6;
    const int lane = tid & 63;
    const int sub = lane & 15;
    const int gslot = wave * 4 + (lane >> 4);   // 0..15
    const int cb = sub * 8;

    float we0[8], at0[8];
    #pragma unroll
    for (int i = 0; i < 8; ++i) { we0[i] = W_e[cb + i]; at0[i] = att[cb + i]; }

    float acc[8];
    #pragma unroll
    for (int i = 0; i < 8; ++i) acc[i] = 0.f;

    for (int v = gslot; v < NNODES; v += 16) {
        const float* xrp = xr_all + (size_t)(base_n + v) * NCH + cb;
        float4 xr0 = *reinterpret_cast<const float4*>(xrp);
        float4 xr1 = *reinterpret_cast<const float4*>(xrp + 4);
        const int lo = off_s[v], hi = off_s[v + 1];
        float m = -INFINITY, ssum = 0.f;
        for (int sl = lo; sl < hi; ++sl) {
            int src = csr_src[sl];
            float a = csr_attr[sl];
            float4 x0 = *reinterpret_cast<const float4*>(&xl_s[src * NCH + cb]);
            float4 x1 = *reinterpret_cast<const float4*>(&xl_s[src * NCH + cb + 4]);
            float mi, t = 0.f;
            mi = x0.x + xr0.x + a * we0[0]; t += (mi >= 0.f ? mi : 0.2f * mi) * at0[0];
            mi = x0.y + xr0.y + a * we0[1]; t += (mi >= 0.f ? mi : 0.2f * mi) * at0[1];
            mi = x0.z + xr0.z + a * we0[2]; t += (mi >= 0.f ? mi : 0.2f * mi) * at0[2];
            mi = x0.w + xr0.w + a * we0[3]; t += (mi >= 0.f ? mi : 0.2f * mi) * at0[3];
            mi = x1.x + xr1.x + a * we0[4]; t += (mi >= 0.f ? mi : 0.2f * mi) * at0[4];
            mi = x1.y + xr1.y + a * we0[5]; t += (mi >= 0.f ? mi : 0.2f * mi) * at0[5];
            mi = x1.z + xr1.z + a * we0[6]; t += (mi >= 0.f ? mi : 0.2f * mi) * at0[6];
            mi = x1.w + xr1.w + a * we0[7]; t += (mi >= 0.f ? mi : 0.2f * mi) * at0[7];
            t += __shfl_xor(t, 1, 64);
            t += __shfl_xor(t, 2, 64);
            t += __shfl_xor(t, 4, 64);
            t += __shfl_xor(t, 8, 64);
            if (sub == 0) csr_e[sl] = t;
            float mn = fmaxf(m, t);
            ssum = ssum * __expf(m - mn) + __expf(t - mn);
            m = mn;
        }
        float inv = 1.f / ssum;
        for (int sl = lo; sl < hi; ++sl) {
            int src = csr_src[sl];
            float al = __expf(csr_e[sl] - m) * inv;
            float4 x0 = *reinterpret_cast<const float4*>(&xl_s[src * NCH + cb]);
            float4 x1 = *reinterpret_cast<const float4*>(&xl_s[src * NCH + cb + 4]);
            acc[0] += al * x0.x; acc[1] += al * x0.y;
            acc[2] += al * x0.z; acc[3] += al * x0.w;
            acc[4] += al * x1.x; acc[5] += al * x1.y;
            acc[6] += al * x1.z; acc[7] += al * x1.w;
        }
    }
    #pragma unroll
    for (int i = 0; i < 8; ++i) {
        acc[i] += __shfl_xor(acc[i], 16, 64);
        acc[i] += __shfl_xor(acc[i], 32, 64);
    }
    if ((lane >> 4) == 0) {
        *reinterpret_cast<float4*>(&gacc_s[wave * NCH + cb]) =
            make_float4(acc[0], acc[1], acc[2], acc[3]);
        *reinterpret_cast<float4*>(&gacc_s[wave * NCH + cb + 4]) =
            make_float4(acc[4], acc[5], acc[6], acc[7]);
    }
    __syncthreads();

    for (int c = tid; c < NCH; c += 256) {
        float v = (gacc_s[c] + gacc_s[NCH + c] + gacc_s[2 * NCH + c] + gacc_s[3 * NCH + c])
                      * (1.f / NNODES) + bias_out[c];
        g_all[(size_t)g * NCH + c] = v;
    }
}

// ---------------- gx_all = g_all @ W_ih^T + biases; also zeroes h_pub (replay-safe) ------
__global__ void k_gx(const float* __restrict__ g_all, const float* __restrict__ W_ihT,
                     const float* __restrict__ b_ih, const float* __restrict__ b_hh,
                     float* __restrict__ gx_all, unsigned long long* __restrict__ h_pub) {
    if (blockIdx.x < 32)
        h_pub[(size_t)blockIdx.x * 256 + threadIdx.x] = 0ull;   // 8192 u64 total
    int idx = blockIdx.x * blockDim.x + threadIdx.x;   // over 800*768
    if (idx >= NGRAPH * 3 * NH) return;
    int gi = idx / (3 * NH);
    int o = idx - gi * (3 * NH);
    float acc = b_ih[o] + (o < 2 * NH ? b_hh[o] : 0.f);  // n-gate b_hh stays separate
    const float* grow = g_all + (size_t)gi * NCH;
    for (int c = 0; c < NCH; ++c) acc += grow[c] * W_ihT[c * (3 * NH) + o];
    gx_all[idx] = acc;
}

// ---------------- GRU: 256 blocks (16 batch x 16 slice) — r11-proven, unchanged ----------
__launch_bounds__(256, 1)
__global__ void k_gru(const float* __restrict__ gx_all, const float* __restrict__ W_hh,
                      const float* __restrict__ b_hh, float* __restrict__ h_all,
                      unsigned long long* __restrict__ h_pub) {
    __shared__ __align__(16) float h_s[NH];
    __shared__ float gh_s[48];
    __shared__ float gx_s[2][48];

    const int bid = blockIdx.x;
    const int b = bid >> 4;
    const int s = bid & 15;
    const int tid = threadIdx.x;
    const int wv = tid >> 6;
    const int g = tid >> 2;          // row 0..47 (tid<192)
    const int l = tid & 3;           // k-quarter within row

    float4 Wv[16];
    if (tid < 192) {
        int row = (g < 16) ? (NSL * s + g)
                : (g < 32) ? (NH + NSL * s + (g - 16))
                           : (2 * NH + NSL * s + (g - 32));
        const float* wr = W_hh + (size_t)row * NH + 64 * l;
        #pragma unroll
        for (int j = 0; j < 16; ++j) {
            int jeff = (j + 2 * l) & 15;           // bank-stagger (conflict-free h reads)
            Wv[j] = *reinterpret_cast<const float4*>(wr + 4 * jeff);
        }
    }
    const float bhn = (tid < NSL) ? b_hh[2 * NH + NSL * s + tid] : 0.f;
    const int own_lo = NSL * s, own_hi = NSL * s + NSL;

    for (int i = tid; i < NH; i += 256) h_s[i] = 0.f;
    if (wv == 3) {
        int i = tid - 192;
        if (i < 48) {
            int o = (i < 16) ? (NSL * s + i) : (i < 32) ? (NH + NSL * s + i - 16)
                                                        : (2 * NH + NSL * s + i - 32);
            gx_s[0][i] = gx_all[(size_t)(b * NT + 0) * (3 * NH) + o];
        }
    }
    __syncthreads();

    for (int t = 0; t < NT; ++t) {
        if (wv == 3) {
            int i = tid - 192;
            if (i < 48 && t + 1 < NT) {
                int o = (i < 16) ? (NSL * s + i) : (i < 32) ? (NH + NSL * s + i - 16)
                                                            : (2 * NH + NSL * s + i - 32);
                gx_s[(t + 1) & 1][i] = gx_all[(size_t)(b * NT + t + 1) * (3 * NH) + o];
            }
        } else {
            float a0 = 0.f, a1 = 0.f, a2 = 0.f, a3 = 0.f;
            #pragma unroll
            for (int j = 0; j < 16; ++j) {
                int jeff = (j + 2 * l) & 15;
                float4 hv = *reinterpret_cast<const float4*>(&h_s[64 * l + 4 * jeff]);
                float4 w = Wv[j];
                a0 += w.x * hv.x; a1 += w.y * hv.y; a2 += w.z * hv.z; a3 += w.w * hv.w;
            }
            float acc = (a0 + a1) + (a2 + a3);
            acc += __shfl_xor(acc, 1, 64);
            acc += __shfl_xor(acc, 2, 64);
            if (l == 0) gh_s[g] = acc;
        }
        __syncthreads();

        const int par = (t + 1) & 1;
        if (tid < NSL) {
            const float* gx = gx_s[t & 1];
            float r = 1.f / (1.f + expf(-(gx[tid] + gh_s[tid])));
            float z = 1.f / (1.f + expf(-(gx[16 + tid] + gh_s[16 + tid])));
            float n = tanhf(gx[32 + tid] + r * (gh_s[32 + tid] + bhn));
            int o = own_lo + tid;
            float hv = (1.f - z) * n + z * h_s[o];
            h_all[(size_t)(b * NT + t) * NH + o] = hv;
            unsigned long long w = ((unsigned long long)(unsigned)(t + 1) << 32)
                                 | (unsigned long long)__float_as_uint(hv);
            __hip_atomic_store(&h_pub[((size_t)b * 2 + par) * NH + o], w,
                               __ATOMIC_RELAXED, __HIP_MEMORY_SCOPE_AGENT);
            h_s[o] = hv;
        }
        if (tid < own_lo || tid >= own_hi) {
            const unsigned long long* p = &h_pub[((size_t)b * 2 + par) * NH + tid];
            unsigned long long w;
            const unsigned target = (unsigned)(t + 1);
            while ((unsigned)((w = __hip_atomic_load(p, __ATOMIC_RELAXED,
                                                     __HIP_MEMORY_SCOPE_AGENT)) >> 32) != target)
                __builtin_amdgcn_s_sleep(1);
            h_s[tid] = __uint_as_float((unsigned)w);
        }
        __syncthreads();
    }
}

// ---------------- classifier: scores[b,t,:] = relu(h @ W1 + b1) @ W2 + b2 ----------------
__launch_bounds__(128)
__global__ void k_cls(const float* __restrict__ h_all,
                      const float* __restrict__ W1, const float* __restrict__ b1,
                      const float* __restrict__ W2, const float* __restrict__ b2,
                      float* __restrict__ sc_all) {
    __shared__ float h_s[NH];
    __shared__ float s1_s[NH / 2];
    const int bt = blockIdx.x;
    const int tid = threadIdx.x;
    h_s[tid] = h_all[(size_t)bt * NH + tid];
    h_s[tid + 128] = h_all[(size_t)bt * NH + tid + 128];
    __syncthreads();
    float acc = b1[tid];
    #pragma unroll 8
    for (int k = 0; k < NH; ++k) acc += h_s[k] * W1[k * (NH / 2) + tid];
    s1_s[tid] = fmaxf(acc, 0.f);
    __syncthreads();
    if (tid < NCLS) {
        float a = b2[tid];
        for (int k = 0; k < NH / 2; ++k) a += s1_s[k] * W2[k * NCLS + tid];
        sc_all[bt * NCLS + tid] = a;
    }
}

// ---------------- top-k over time per (b, class) ----------------
__global__ void k_topk(const float* __restrict__ sc_all, float* __restrict__ out) {
    int tid = threadIdx.x;
    if (tid >= NB * NCLS) return;
    int b = tid / NCLS;
    int c = tid - b * NCLS;
    float vals[NT];
    for (int t = 0; t < NT; ++t) vals[t] = sc_all[(b * NT + t) * NCLS + c];
    float sum = 0.f;
    for (int k = 0; k < NTOPK; ++k) {
        float best = -INFINITY; int bi = 0;
        for (int t = 0; t < NT; ++t) {
            if (vals[t] > best) { best = vals[t]; bi = t; }
        }
        vals[bi] = -INFINITY;
        sum += best;
        out[NB * NCLS + b * (NTOPK * NCLS) + k * NCLS + c] = (float)bi;
    }
    out[b * NCLS + c] = sum * (1.f / NTOPK);
}

extern "C" void kernel_launch(void* const* d_in, const int* in_sizes, int n_in,
                              void* d_out, int out_size, void* d_ws, size_t ws_size,
                              hipStream_t stream) {
    const float* x        = (const float*)d_in[0];
    const int*   ei       = (const int*)  d_in[1];
    const float* eattr    = (const float*)d_in[2];
    const float* W_l      = (const float*)d_in[3];
    const float* b_l      = (const float*)d_in[4];
    const float* W_r      = (const float*)d_in[5];
    const float* b_r      = (const float*)d_in[6];
    const float* W_e      = (const float*)d_in[7];
    const float* att      = (const float*)d_in[8];
    const float* bias_out = (const float*)d_in[9];
    const float* W_ih     = (const float*)d_in[10];
    const float* W_hh     = (const float*)d_in[11];
    const float* b_ih     = (const float*)d_in[12];
    const float* b_hh     = (const float*)d_in[13];
    const float* W1       = (const float*)d_in[14];
    const float* b1       = (const float*)d_in[15];
    const float* W2       = (const float*)d_in[16];
    const float* b2       = (const float*)d_in[17];
    float* out = (float*)d_out;

    float* ws = (float*)d_ws;
    float* xr_all = ws;                                   // 49600*128 (dead after k_gat)
    float* xl_all = xr_all + (size_t)NTOTAL * NCH;        // 49600*128 (dead after k_gat)
    float* g_all  = xl_all + (size_t)NTOTAL * NCH;        // 800*128
    float* gx_all = g_all + NGRAPH * NCH;                 // 800*768
    float* W_ihT  = gx_all + NGRAPH * 3 * NH;             // 128*768
    float* h_all  = W_ihT + NCH * 3 * NH;                 // 800*256
    float* sc_all = h_all + (size_t)NGRAPH * NH;          // 800*3
    // packed h-exchange buffer aliases the (dead-after-gat) xr_all region
    unsigned long long* h_pub = (unsigned long long*)xr_all;   // 16*2*256 u64 = 64 KB

    k_xrl<<<NXB + TTB, 512, 0, stream>>>(x, W_r, b_r, W_l, b_l, W_ih, W_ihT, xr_all, xl_all);
    k_gat<<<NGRAPH, 256, 0, stream>>>(ei, eattr, W_e, att, bias_out, xr_all, xl_all, g_all);
    k_gx<<<(NGRAPH * 3 * NH + 255) / 256, 256, 0, stream>>>(g_all, W_ihT, b_ih, b_hh,
                                                            gx_all, h_pub);
    k_gru<<<NB * NSL, 256, 0, stream>>>(gx_all, W_hh, b_hh, h_all, h_pub);
    k_cls<<<NB * NT, 128, 0, stream>>>(h_all, W1, b1, W2, b2, sc_all);
    k_topk<<<1, 64, 0, stream>>>(sc_all, out);
}

// Round 13
// 212.073 us; speedup vs baseline: 3.4458x; 1.0001x over previous
//
#include <hip/hip_runtime.h>
#include <math.h>

#define NNODES 62
#define NDEG 8
#define NGRAPH 800
#define NB 16
#define NT 50
#define NIN 64
#define NCH 128
#define NH 256
#define NCLS 3
#define NTOPK 5
#define NSL 16                  // h-slices per batch (blocks per sequence)
#define EPG (NNODES*NDEG)       // 496 edges per graph
#define E2G (EPG + NNODES)      // 558 incl self loops
#define NTOTAL (NGRAPH*NNODES)  // 49600
#define ETOTAL (NGRAPH*EPG)     // 396800
#define NXB (NTOTAL/64)         // 775 main xrl blocks
#define TTB 96                  // transpose tail blocks appended to k_xrl grid

// async 1KB wave copy: global (per-lane src base+lane*16) -> LDS (uniform base+lane*16)
__device__ __forceinline__ void load_lds_1k(const void* g, void* lds, int lane) {
    __builtin_amdgcn_global_load_lds(
        (const __attribute__((address_space(1))) unsigned int*)((const char*)g + lane * 16),
        (__attribute__((address_space(3))) unsigned int*)lds, 16, 0, 0);
}

// ---------------- xr = x@W_r + b_r AND xl = x@W_l + b_l ----------------
// Staging now via global_load_lds (no VGPR round trip, one drain). Compute = r12.
__launch_bounds__(512, 4)
__global__ void k_xrl(const float* __restrict__ x,
                      const float* __restrict__ W_r, const float* __restrict__ b_r,
                      const float* __restrict__ W_l, const float* __restrict__ b_l,
                      const float* __restrict__ W_ih, float* __restrict__ W_ihT,
                      float* __restrict__ xr, float* __restrict__ xl) {
    __shared__ __align__(16) float x_s[64 * NIN];      // 16 KB
    __shared__ __align__(16) float wr_s[NIN * NCH];    // 32 KB
    __shared__ __align__(16) float wl_s[NIN * NCH];    // 32 KB
    const int blk = blockIdx.x;
    const int tid = threadIdx.x;
    if (blk >= NXB) {
        for (int idx = (blk - NXB) * 512 + tid; idx < 3 * NH * NCH; idx += TTB * 512) {
            int r = idx / NCH, c = idx - r * NCH;
            W_ihT[c * (3 * NH) + r] = W_ih[idx];
        }
        return;
    }
    const int base_v = blk * 64;

    {   // 80 x 1KB chunks: wr_s (32), wl_s (32), x_s (16); 10 issues per wave
        const int wid = tid >> 6, lane = tid & 63;
        const char* xg = (const char*)(x + (size_t)base_v * NIN);
        #pragma unroll
        for (int c0 = 0; c0 < 10; ++c0) {
            int c = wid * 10 + c0;
            if (c < 32)
                load_lds_1k((const char*)W_r + c * 1024, (char*)wr_s + c * 1024, lane);
            else if (c < 64)
                load_lds_1k((const char*)W_l + (c - 32) * 1024, (char*)wl_s + (c - 32) * 1024, lane);
            else
                load_lds_1k(xg + (c - 64) * 1024, (char*)x_s + (c - 64) * 1024, lane);
        }
    }
    __syncthreads();

    const int c4 = (tid & 31) * 4;
    const int ng = tid >> 5;          // 0..15 -> nodes ng*4 .. ng*4+3
    float4 aR[4], aL[4];
    float4 br4 = *reinterpret_cast<const float4*>(b_r + c4);
    float4 bl4 = *reinterpret_cast<const float4*>(b_l + c4);
    #pragma unroll
    for (int j = 0; j < 4; ++j) { aR[j] = br4; aL[j] = bl4; }

    const float* xs = x_s + (ng * 4) * NIN;
    for (int k4 = 0; k4 < NIN; k4 += 4) {
        float4 xv[4];
        #pragma unroll
        for (int j = 0; j < 4; ++j)
            xv[j] = *reinterpret_cast<const float4*>(&xs[j * NIN + k4]);   // broadcast b128
        #pragma unroll
        for (int kk = 0; kk < 4; ++kk) {
            float4 wr = *reinterpret_cast<const float4*>(&wr_s[(k4 + kk) * NCH + c4]);
            float4 wl = *reinterpret_cast<const float4*>(&wl_s[(k4 + kk) * NCH + c4]);
            #pragma unroll
            for (int j = 0; j < 4; ++j) {
                float xk = (kk == 0) ? xv[j].x : (kk == 1) ? xv[j].y
                         : (kk == 2) ? xv[j].z : xv[j].w;
                aR[j].x += xk * wr.x; aR[j].y += xk * wr.y;
                aR[j].z += xk * wr.z; aR[j].w += xk * wr.w;
                aL[j].x += xk * wl.x; aL[j].y += xk * wl.y;
                aL[j].z += xk * wl.z; aL[j].w += xk * wl.w;
            }
        }
    }
    #pragma unroll
    for (int j = 0; j < 4; ++j) {
        int v = base_v + ng * 4 + j;
        *reinterpret_cast<float4*>(xr + (size_t)v * NCH + c4) = aR[j];
        *reinterpret_cast<float4*>(xl + (size_t)v * NCH + c4) = aL[j];
    }
}

// ---------------- fused per-graph GATv2 + mean pool: CSR-bucketed (r8-proven) ------------
// xl tile staged via global_load_lds (31 x 1KB chunks).
__launch_bounds__(256, 4)
__global__ void k_gat(const int* __restrict__ ei, const float* __restrict__ eattr,
                      const float* __restrict__ W_e, const float* __restrict__ att,
                      const float* __restrict__ bias_out,
                      const float* __restrict__ xr_all, const float* __restrict__ xl_all,
                      float* __restrict__ g_all) {
    __shared__ __align__(16) float xl_s[NNODES * NCH];  // 31744 B = 31 x 1024
    __shared__ unsigned short csr_src[E2G];
    __shared__ float csr_attr[E2G];
    __shared__ float csr_e[E2G];
    __shared__ unsigned short off_s[NNODES + 2];
    __shared__ unsigned cur_s[NNODES];
    __shared__ unsigned cnt_s[NNODES];
    __shared__ float asum_s[NNODES];
    __shared__ float la_s[NNODES];
    __shared__ float gacc_s[4 * NCH];

    const int g = blockIdx.x;
    const int tid = threadIdx.x;
    const int base_e = g * EPG;
    const int base_n = g * NNODES;

    {   // async xl tile stage
        const int wid = tid >> 6, lane = tid & 63;
        const char* src = (const char*)(xl_all + (size_t)base_n * NCH);
        for (int c = wid; c < 31; c += 4)
            load_lds_1k(src + c * 1024, (char*)xl_s + c * 1024, lane);
    }
    for (int v = tid; v < NNODES; v += 256) { asum_s[v] = 0.f; cnt_s[v] = 0u; cur_s[v] = 0u; }
    int s0 = -1, d0 = 0, s1 = -1, d1 = 0;
    float a0 = 0.f, a1 = 0.f;
    {
        int j0 = tid * 2, j1 = tid * 2 + 1;
        if (j0 < EPG) { s0 = ei[base_e + j0] - base_n; d0 = ei[ETOTAL + base_e + j0] - base_n; a0 = eattr[base_e + j0]; }
        if (j1 < EPG) { s1 = ei[base_e + j1] - base_n; d1 = ei[ETOTAL + base_e + j1] - base_n; a1 = eattr[base_e + j1]; }
    }
    __syncthreads();

    if (s0 >= 0) { atomicAdd(&cnt_s[d0], 1u); atomicAdd(&asum_s[d0], a0); }
    if (s1 >= 0) { atomicAdd(&cnt_s[d1], 1u); atomicAdd(&asum_s[d1], a1); }
    __syncthreads();

    if (tid < 64) {
        unsigned val = (tid < NNODES) ? (cnt_s[tid] + 1u) : 0u;
        unsigned xsc = val;
        #pragma unroll
        for (int dlt = 1; dlt < 64; dlt <<= 1) {
            unsigned o = __shfl_up(xsc, dlt, 64);
            if (tid >= dlt) xsc += o;
        }
        if (tid < NNODES) {
            off_s[tid] = (unsigned short)(xsc - val);
            la_s[tid] = asum_s[tid] / fmaxf((float)cnt_s[tid], 1.f);
        }
        if (tid == NNODES - 1) off_s[NNODES] = (unsigned short)xsc;
    }
    __syncthreads();

    if (s0 >= 0) { int sl = off_s[d0] + (int)atomicAdd(&cur_s[d0], 1u); csr_src[sl] = (unsigned short)s0; csr_attr[sl] = a0; }
    if (s1 >= 0) { int sl = off_s[d1] + (int)atomicAdd(&cur_s[d1], 1u); csr_src[sl] = (unsigned short)s1; csr_attr[sl] = a1; }
    if (tid < NNODES) { int sl = off_s[tid + 1] - 1; csr_src[sl] = (unsigned short)tid; csr_attr[sl] = la_s[tid]; }
    __syncthreads();

    const int wave = tid >> 6;
    const int lane = tid & 63;
    const int sub = lane & 15;
    const int gslot = wave * 4 + (lane >> 4);   // 0..15
    const int cb = sub * 8;

    float we0[8], at0[8];
    #pragma unroll
    for (int i = 0; i < 8; ++i) { we0[i] = W_e[cb + i]; at0[i] = att[cb + i]; }

    float acc[8];
    #pragma unroll
    for (int i = 0; i < 8; ++i) acc[i] = 0.f;

    for (int v = gslot; v < NNODES; v += 16) {
        const float* xrp = xr_all + (size_t)(base_n + v) * NCH + cb;
        float4 xr0 = *reinterpret_cast<const float4*>(xrp);
        float4 xr1 = *reinterpret_cast<const float4*>(xrp + 4);
        const int lo = off_s[v], hi = off_s[v + 1];
        float m = -INFINITY, ssum = 0.f;
        for (int sl = lo; sl < hi; ++sl) {
            int src = csr_src[sl];
            float a = csr_attr[sl];
            float4 x0 = *reinterpret_cast<const float4*>(&xl_s[src * NCH + cb]);
            float4 x1 = *reinterpret_cast<const float4*>(&xl_s[src * NCH + cb + 4]);
            float mi, t = 0.f;
            mi = x0.x + xr0.x + a * we0[0]; t += (mi >= 0.f ? mi : 0.2f * mi) * at0[0];
            mi = x0.y + xr0.y + a * we0[1]; t += (mi >= 0.f ? mi : 0.2f * mi) * at0[1];
            mi = x0.z + xr0.z + a * we0[2]; t += (mi >= 0.f ? mi : 0.2f * mi) * at0[2];
            mi = x0.w + xr0.w + a * we0[3]; t += (mi >= 0.f ? mi : 0.2f * mi) * at0[3];
            mi = x1.x + xr1.x + a * we0[4]; t += (mi >= 0.f ? mi : 0.2f * mi) * at0[4];
            mi = x1.y + xr1.y + a * we0[5]; t += (mi >= 0.f ? mi : 0.2f * mi) * at0[5];
            mi = x1.z + xr1.z + a * we0[6]; t += (mi >= 0.f ? mi : 0.2f * mi) * at0[6];
            mi = x1.w + xr1.w + a * we0[7]; t += (mi >= 0.f ? mi : 0.2f * mi) * at0[7];
            t += __shfl_xor(t, 1, 64);
            t += __shfl_xor(t, 2, 64);
            t += __shfl_xor(t, 4, 64);
            t += __shfl_xor(t, 8, 64);
            if (sub == 0) csr_e[sl] = t;
            float mn = fmaxf(m, t);
            ssum = ssum * __expf(m - mn) + __expf(t - mn);
            m = mn;
        }
        float inv = 1.f / ssum;
        for (int sl = lo; sl < hi; ++sl) {
            int src = csr_src[sl];
            float al = __expf(csr_e[sl] - m) * inv;
            float4 x0 = *reinterpret_cast<const float4*>(&xl_s[src * NCH + cb]);
            float4 x1 = *reinterpret_cast<const float4*>(&xl_s[src * NCH + cb + 4]);
            acc[0] += al * x0.x; acc[1] += al * x0.y;
            acc[2] += al * x0.z; acc[3] += al * x0.w;
            acc[4] += al * x1.x; acc[5] += al * x1.y;
            acc[6] += al * x1.z; acc[7] += al * x1.w;
        }
    }
    #pragma unroll
    for (int i = 0; i < 8; ++i) {
        acc[i] += __shfl_xor(acc[i], 16, 64);
        acc[i] += __shfl_xor(acc[i], 32, 64);
    }
    if ((lane >> 4) == 0) {
        *reinterpret_cast<float4*>(&gacc_s[wave * NCH + cb]) =
            make_float4(acc[0], acc[1], acc[2], acc[3]);
        *reinterpret_cast<float4*>(&gacc_s[wave * NCH + cb + 4]) =
            make_float4(acc[4], acc[5], acc[6], acc[7]);
    }
    __syncthreads();

    for (int c = tid; c < NCH; c += 256) {
        float v = (gacc_s[c] + gacc_s[NCH + c] + gacc_s[2 * NCH + c] + gacc_s[3 * NCH + c])
                      * (1.f / NNODES) + bias_out[c];
        g_all[(size_t)g * NCH + c] = v;
    }
}

// ---------------- gx_all = g_all @ W_ih^T + biases; also zeroes h_pub (replay-safe) ------
__global__ void k_gx(const float* __restrict__ g_all, const float* __restrict__ W_ihT,
                     const float* __restrict__ b_ih, const float* __restrict__ b_hh,
                     float* __restrict__ gx_all, unsigned long long* __restrict__ h_pub) {
    if (blockIdx.x < 32)
        h_pub[(size_t)blockIdx.x * 256 + threadIdx.x] = 0ull;   // 8192 u64 total
    int idx = blockIdx.x * blockDim.x + threadIdx.x;   // over 800*768
    if (idx >= NGRAPH * 3 * NH) return;
    int gi = idx / (3 * NH);
    int o = idx - gi * (3 * NH);
    float acc = b_ih[o] + (o < 2 * NH ? b_hh[o] : 0.f);  // n-gate b_hh stays separate
    const float* grow = g_all + (size_t)gi * NCH;
    for (int c = 0; c < NCH; ++c) acc += grow[c] * W_ihT[c * (3 * NH) + o];
    gx_all[idx] = acc;
}

// ---------------- GRU: 256 blocks (16 batch x 16 slice) — r11-proven, unchanged ----------
__launch_bounds__(256, 1)
__global__ void k_gru(const float* __restrict__ gx_all, const float* __restrict__ W_hh,
                      const float* __restrict__ b_hh, float* __restrict__ h_all,
                      unsigned long long* __restrict__ h_pub) {
    __shared__ __align__(16) float h_s[NH];
    __shared__ float gh_s[48];
    __shared__ float gx_s[2][48];

    const int bid = blockIdx.x;
    const int b = bid >> 4;
    const int s = bid & 15;
    const int tid = threadIdx.x;
    const int wv = tid >> 6;
    const int g = tid >> 2;          // row 0..47 (tid<192)
    const int l = tid & 3;           // k-quarter within row

    float4 Wv[16];
    if (tid < 192) {
        int row = (g < 16) ? (NSL * s + g)
                : (g < 32) ? (NH + NSL * s + (g - 16))
                           : (2 * NH + NSL * s + (g - 32));
        const float* wr = W_hh + (size_t)row * NH + 64 * l;
        #pragma unroll
        for (int j = 0; j < 16; ++j) {
            int jeff = (j + 2 * l) & 15;           // bank-stagger (conflict-free h reads)
            Wv[j] = *reinterpret_cast<const float4*>(wr + 4 * jeff);
        }
    }
    const float bhn = (tid < NSL) ? b_hh[2 * NH + NSL * s + tid] : 0.f;
    const int own_lo = NSL * s, own_hi = NSL * s + NSL;

    for (int i = tid; i < NH; i += 256) h_s[i] = 0.f;
    if (wv == 3) {
        int i = tid - 192;
        if (i < 48) {
            int o = (i < 16) ? (NSL * s + i) : (i < 32) ? (NH + NSL * s + i - 16)
                                                        : (2 * NH + NSL * s + i - 32);
            gx_s[0][i] = gx_all[(size_t)(b * NT + 0) * (3 * NH) + o];
        }
    }
    __syncthreads();

    for (int t = 0; t < NT; ++t) {
        if (wv == 3) {
            int i = tid - 192;
            if (i < 48 && t + 1 < NT) {
                int o = (i < 16) ? (NSL * s + i) : (i < 32) ? (NH + NSL * s + i - 16)
                                                            : (2 * NH + NSL * s + i - 32);
                gx_s[(t + 1) & 1][i] = gx_all[(size_t)(b * NT + t + 1) * (3 * NH) + o];
            }
        } else {
            float a0 = 0.f, a1 = 0.f, a2 = 0.f, a3 = 0.f;
            #pragma unroll
            for (int j = 0; j < 16; ++j) {
                int jeff = (j + 2 * l) & 15;
                float4 hv = *reinterpret_cast<const float4*>(&h_s[64 * l + 4 * jeff]);
                float4 w = Wv[j];
                a0 += w.x * hv.x; a1 += w.y * hv.y; a2 += w.z * hv.z; a3 += w.w * hv.w;
            }
            float acc = (a0 + a1) + (a2 + a3);
            acc += __shfl_xor(acc, 1, 64);
            acc += __shfl_xor(acc, 2, 64);
            if (l == 0) gh_s[g] = acc;
        }
        __syncthreads();

        const int par = (t + 1) & 1;
        if (tid < NSL) {
            const float* gx = gx_s[t & 1];
            float r = 1.f / (1.f + expf(-(gx[tid] + gh_s[tid])));
            float z = 1.f / (1.f + expf(-(gx[16 + tid] + gh_s[16 + tid])));
            float n = tanhf(gx[32 + tid] + r * (gh_s[32 + tid] + bhn));
            int o = own_lo + tid;
            float hv = (1.f - z) * n + z * h_s[o];
            h_all[(size_t)(b * NT + t) * NH + o] = hv;
            unsigned long long w = ((unsigned long long)(unsigned)(t + 1) << 32)
                                 | (unsigned long long)__float_as_uint(hv);
            __hip_atomic_store(&h_pub[((size_t)b * 2 + par) * NH + o], w,
                               __ATOMIC_RELAXED, __HIP_MEMORY_SCOPE_AGENT);
            h_s[o] = hv;
        }
        if (tid < own_lo || tid >= own_hi) {
            const unsigned long long* p = &h_pub[((size_t)b * 2 + par) * NH + tid];
            unsigned long long w;
            const unsigned target = (unsigned)(t + 1);
            while ((unsigned)((w = __hip_atomic_load(p, __ATOMIC_RELAXED,
                                                     __HIP_MEMORY_SCOPE_AGENT)) >> 32) != target)
                __builtin_amdgcn_s_sleep(1);
            h_s[tid] = __uint_as_float((unsigned)w);
        }
        __syncthreads();
    }
}

// ---------------- classifier: scores[b,t,:] = relu(h @ W1 + b1) @ W2 + b2 ----------------
__launch_bounds__(128)
__global__ void k_cls(const float* __restrict__ h_all,
                      const float* __restrict__ W1, const float* __restrict__ b1,
                      const float* __restrict__ W2, const float* __restrict__ b2,
                      float* __restrict__ sc_all) {
    __shared__ float h_s[NH];
    __shared__ float s1_s[NH / 2];
    const int bt = blockIdx.x;
    const int tid = threadIdx.x;
    h_s[tid] = h_all[(size_t)bt * NH + tid];
    h_s[tid + 128] = h_all[(size_t)bt * NH + tid + 128];
    __syncthreads();
    float acc = b1[tid];
    #pragma unroll 8
    for (int k = 0; k < NH; ++k) acc += h_s[k] * W1[k * (NH / 2) + tid];
    s1_s[tid] = fmaxf(acc, 0.f);
    __syncthreads();
    if (tid < NCLS) {
        float a = b2[tid];
        for (int k = 0; k < NH / 2; ++k) a += s1_s[k] * W2[k * NCLS + tid];
        sc_all[bt * NCLS + tid] = a;
    }
}

// ---------------- top-k over time per (b, class) ----------------
__global__ void k_topk(const float* __restrict__ sc_all, float* __restrict__ out) {
    int tid = threadIdx.x;
    if (tid >= NB * NCLS) return;
    int b = tid / NCLS;
    int c = tid - b * NCLS;
    float vals[NT];
    for (int t = 0; t < NT; ++t) vals[t] = sc_all[(b * NT + t) * NCLS + c];
    float sum = 0.f;
    for (int k = 0; k < NTOPK; ++k) {
        float best = -INFINITY; int bi = 0;
        for (int t = 0; t < NT; ++t) {
            if (vals[t] > best) { best = vals[t]; bi = t; }
        }
        vals[bi] = -INFINITY;
        sum += best;
        out[NB * NCLS + b * (NTOPK * NCLS) + k * NCLS + c] = (float)bi;
    }
    out[b * NCLS + c] = sum * (1.f / NTOPK);
}

extern "C" void kernel_launch(void* const* d_in, const int* in_sizes, int n_in,
                              void* d_out, int out_size, void* d_ws, size_t ws_size,
                              hipStream_t stream) {
    const float* x        = (const float*)d_in[0];
    const int*   ei       = (const int*)  d_in[1];
    const float* eattr    = (const float*)d_in[2];
    const float* W_l      = (const float*)d_in[3];
    const float* b_l      = (const float*)d_in[4];
    const float* W_r      = (const float*)d_in[5];
    const float* b_r      = (const float*)d_in[6];
    const float* W_e      = (const float*)d_in[7];
    const float* att      = (const float*)d_in[8];
    const float* bias_out = (const float*)d_in[9];
    const float* W_ih     = (const float*)d_in[10];
    const float* W_hh     = (const float*)d_in[11];
    const float* b_ih     = (const float*)d_in[12];
    const float* b_hh     = (const float*)d_in[13];
    const float* W1       = (const float*)d_in[14];
    const float* b1       = (const float*)d_in[15];
    const float* W2       = (const float*)d_in[16];
    const float* b2       = (const float*)d_in[17];
    float* out = (float*)d_out;

    float* ws = (float*)d_ws;
    float* xr_all = ws;                                   // 49600*128 (dead after k_gat)
    float* xl_all = xr_all + (size_t)NTOTAL * NCH;        // 49600*128 (dead after k_gat)
    float* g_all  = xl_all + (size_t)NTOTAL * NCH;        // 800*128
    float* gx_all = g_all + NGRAPH * NCH;                 // 800*768
    float* W_ihT  = gx_all + NGRAPH * 3 * NH;             // 128*768
    float* h_all  = W_ihT + NCH * 3 * NH;                 // 800*256
    float* sc_all = h_all + (size_t)NGRAPH * NH;          // 800*3
    // packed h-exchange buffer aliases the (dead-after-gat) xr_all region
    unsigned long long* h_pub = (unsigned long long*)xr_all;   // 16*2*256 u64 = 64 KB

    k_xrl<<<NXB + TTB, 512, 0, stream>>>(x, W_r, b_r, W_l, b_l, W_ih, W_ihT, xr_all, xl_all);
    k_gat<<<NGRAPH, 256, 0, stream>>>(ei, eattr, W_e, att, bias_out, xr_all, xl_all, g_all);
    k_gx<<<(NGRAPH * 3 * NH + 255) / 256, 256, 0, stream>>>(g_all, W_ihT, b_ih, b_hh,
                                                            gx_all, h_pub);
    k_gru<<<NB * NSL, 256, 0, stream>>>(gx_all, W_hh, b_hh, h_all, h_pub);
    k_cls<<<NB * NT, 128, 0, stream>>>(h_all, W1, b1, W2, b2, sc_all);
    k_topk<<<1, 64, 0, stream>>>(sc_all, out);
}